// Round 10
// baseline (229.006 us; speedup 1.0000x reference)
//
#include <hip/hip_runtime.h>
#include <math.h>

// [B=2, 1, D=192, H=192, W=192] fp32
#define W 192
#define H 192
#define DEPTH 192
#define BATCH 2
#define TW 64          // tile width
#define TH 16          // tile height
#define DC 12          // output planes per block
#define HW (H * W)
#define VOL ((size_t)DEPTH * HW)
#define NPL (DC + 2)                  // 14 planes swept: d0-1 .. d0+12
#define LROW 72                       // LDS row stride (floats): cols w0-4 .. w0+67
#define LROWS 18                      // halo rows: h0-1 .. h0+16
#define LPLANE (LROW * LROWS)         // 1296 floats per array per plane
#define NITEM 648                     // float4 items/plane: 2 arrays * 18 rows * 18
#define BUFFLOATS 2592                // 648 * 4 floats per plane buffer
#define GX ((W / TW) * (H / TH))      // 3*12 = 36
#define GY (DEPTH / DC)               // 16
#define NBLK (GX * GY * BATCH)        // 1152

// Zero page for OOB DMA sources.
__device__ __align__(16) float g_zero16[16] = {0.f};

// R0-R9 falsified: conflicts, barrier drains, prefetch depth, residency, convoy,
// DRAM pattern (R9: volume is L3-resident). Surviving invariant: VALU-issue ~32us
// conserved, dur tracks TOTAL instruction count -> issue-bound. This kernel cuts
// issue-slots/output ~2x: 4 outputs/thread (2x2, shared stencil rows+cols via
// separable hs/hd), fully-unrolled 14-plane loop (rolling state = SSA renames,
// zero v_movs, all LDS offsets immediate), ds-merged 4-consecutive-float reads.
// Staging: R6-proven global_load_lds + zero-page + raw-barrier, per-plane dbuf.
__global__ __launch_bounds__(256) void sobel_loss_part(
    const float* __restrict__ pred, const float* __restrict__ gt,
    const float* __restrict__ mask, float* __restrict__ partials)
{
    __shared__ __align__(16) float lds[2 * BUFFLOATS];   // 20736 B
    __shared__ float red[4];

    const int tid = threadIdx.x;
    const int tx = blockIdx.x % 3;          // W tile (0..2)
    const int ty = blockIdx.x / 3;          // H tile (0..11)
    const int w0 = tx * TW, h0 = ty * TH;
    const int d0 = blockIdx.y * DC;
    const size_t base = (size_t)blockIdx.z * VOL;

    // thread -> 2x2 outputs: rows t0,t0+1 (tile-local), cols c0,c0+1
    const int rp = tid >> 5;                // 0..7
    const int cp = tid & 31;                // 0..31
    const int t0 = 2 * rp;                  // tile row 0..14
    const int c0 = 2 * cp;                  // tile col 0..62

    // ---- staging geometry (3 DMA slots/thread, loop-invariant) ----
    // j = tid + 256k < 648: a=j/324, e=j%324, r=e/18 (halo row), c=e%18 (col4)
    // LDS float off = 4j == a*1296 + r*72 + 4c (identity with compute reads).
    int it_act[3], it_ok[3];
    size_t it_goff[3];
    const float* it_src[3];
    #pragma unroll
    for (int k = 0; k < 3; ++k) {
        int j = tid + 256 * k;
        int act = (j < NITEM);              // divergent DMA exec-mask: proven R6
        int jj = act ? j : 0;
        int a = jj / 324; int e = jj - a * 324;
        int r = e / 18;   int c = e - r * 18;
        int y  = h0 - 1 + r;
        int xf = w0 - 4 + 4 * c;            // 16B aligned; OOB float4s fully OOB
        it_act[k] = act;
        it_ok[k]  = act && ((unsigned)y < (unsigned)H) && ((unsigned)xf < (unsigned)W);
        it_goff[k] = it_ok[k] ? ((size_t)y * W + xf) : 0;
        it_src[k]  = (jj >= 324) ? gt : pred;
    }

    typedef const __attribute__((address_space(1))) void GV;
    typedef __attribute__((address_space(3))) void LV;

    auto dma_plane = [&](int i) {           // stage plane d0-1+i into buf[i&1]
        const int p = d0 - 1 + i;
        const bool pv = ((unsigned)p < (unsigned)DEPTH);
        float* bufp = lds + (i & 1) * BUFFLOATS;
        #pragma unroll
        for (int k = 0; k < 3; ++k) {
            if (it_act[k]) {
                const float* ga = (pv && it_ok[k])
                    ? (it_src[k] + base + (size_t)p * HW + it_goff[k]) : g_zero16;
                // dest: wave-uniform base 16*(64*wave + 256k) B + lane*16 (HW)
                __builtin_amdgcn_global_load_lds((GV*)ga,
                    (LV*)(bufp + ((tid >> 6) << 8) + (k << 10)), 16, 0, 0);
            }
        }
    };

    // rolling state (constant-indexed after full unroll -> registers)
    float X[2][2][2][3], S[2][2][2][3], Y[2][2][2][3], C[2][2][2][2];
    #pragma unroll
    for (int a = 0; a < 2; ++a)
        #pragma unroll
        for (int o = 0; o < 2; ++o)
            #pragma unroll
            for (int u = 0; u < 2; ++u) {
                X[a][o][u][0]=X[a][o][u][1]=X[a][o][u][2]=0.f;
                S[a][o][u][0]=S[a][o][u][1]=S[a][o][u][2]=0.f;
                Y[a][o][u][0]=Y[a][o][u][1]=Y[a][o][u][2]=0.f;
                C[a][o][u][0]=C[a][o][u][1]=0.f;
            }
    float acc = 0.f;
    float2 Mc[2], Mn[2];
    Mc[0]=Mc[1]=Mn[0]=Mn[1]=make_float2(0.f,0.f);

    // mask pointer for this thread's rows (global rows h0+t0, +1), cols w0+c0..+1
    const float* MB = mask + base + (size_t)(h0 + t0) * W + (w0 + c0);

    dma_plane(0);

    #pragma unroll
    for (int i = 0; i < NPL; ++i) {
        asm volatile("s_waitcnt vmcnt(0)" ::: "memory");
        __builtin_amdgcn_sched_barrier(0);
        __builtin_amdgcn_s_barrier();       // raw barrier (R6-proven pattern)
        __builtin_amdgcn_sched_barrier(0);

        if (i + 1 < NPL) dma_plane(i + 1);

        Mc[0] = Mn[0]; Mc[1] = Mn[1];
        if (i >= 1 && i <= DC) {            // prefetch masks for od = d0+i-1 (used at i+1)
            const float* mp = MB + (size_t)(d0 + i - 1) * HW;
            Mn[0] = *(const float2*)mp;
            Mn[1] = *(const float2*)(mp + W);
        }

        const float* buf = lds + (i & 1) * BUFFLOATS;

        // stage 1: horizontal sums/diffs, shared across the 2 output cols
        float hs[2][4][2], hd[2][4][2], cen[2][2][2];
        #pragma unroll
        for (int a = 0; a < 2; ++a)
            #pragma unroll
            for (int rr = 0; rr < 4; ++rr) {
                const float* bp = buf + a * LPLANE + (t0 + rr) * LROW + (c0 + 3);
                float f0 = bp[0], f1 = bp[1], f2 = bp[2], f3 = bp[3];
                hs[a][rr][0] = f0 + 2.f * f1 + f2;
                hs[a][rr][1] = f1 + 2.f * f2 + f3;
                hd[a][rr][0] = f2 - f0;
                hd[a][rr][1] = f3 - f1;
                if (rr == 1) { cen[a][0][0] = f1; cen[a][0][1] = f2; }
                if (rr == 2) { cen[a][1][0] = f1; cen[a][1][1] = f2; }
            }

        // stage 2: vertical combine -> per-plane X (dx), S (smooth), Y (dy)
        const int ai = i % 3, a1 = (i + 2) % 3, a2 = (i + 1) % 3;  // i, i-1, i-2
        const int ci = i & 1, cm = (i + 1) & 1;                    // i, i-1
        #pragma unroll
        for (int a = 0; a < 2; ++a)
            #pragma unroll
            for (int o = 0; o < 2; ++o)
                #pragma unroll
                for (int u = 0; u < 2; ++u) {
                    X[a][o][u][ai] = hd[a][o][u] + 2.f * hd[a][o+1][u] + hd[a][o+2][u];
                    S[a][o][u][ai] = hs[a][o][u] + 2.f * hs[a][o+1][u] + hs[a][o+2][u];
                    Y[a][o][u][ai] = hs[a][o][u] - hs[a][o+2][u];
                    C[a][o][u][ci] = cen[a][o][u];
                }

        // stage 3: z-combine + loss for output plane od = d0+i-2
        if (i >= 2) {
            #pragma unroll
            for (int o = 0; o < 2; ++o)
                #pragma unroll
                for (int u = 0; u < 2; ++u) {
                    float gxa = X[0][o][u][a2] + 2.f * X[0][o][u][a1] + X[0][o][u][ai];
                    float gya = Y[0][o][u][a2] + 2.f * Y[0][o][u][a1] + Y[0][o][u][ai];
                    float gza = S[0][o][u][a2] - S[0][o][u][ai];
                    float gxb = X[1][o][u][a2] + 2.f * X[1][o][u][a1] + X[1][o][u][ai];
                    float gyb = Y[1][o][u][a2] + 2.f * Y[1][o][u][a1] + Y[1][o][u][ai];
                    float gzb = S[1][o][u][a2] - S[1][o][u][ai];
                    float ga = __builtin_amdgcn_sqrtf(gxa*gxa + gya*gya + gza*gza + 1e-10f);
                    float gb = __builtin_amdgcn_sqrtf(gxb*gxb + gyb*gyb + gzb*gzb + 1e-10f);
                    float m  = u ? Mc[o].y : Mc[o].x;
                    float dm = C[0][o][u][cm] - C[1][o][u][cm];
                    float mse = dm * dm * m;
                    float dg  = gb - ga;
                    float mge = dg * dg * m;
                    // tanh(x) = 1 - 2/(e^{2x}+1), x >= 0
                    float ex = __expf(2.f * mge);
                    float t  = 1.f - 2.f * __builtin_amdgcn_rcpf(ex + 1.f);
                    acc += mse * (1.f + t);
                }
        }
    }

    // block reduction
    float v = acc;
    #pragma unroll
    for (int o = 32; o > 0; o >>= 1) v += __shfl_down(v, o, 64);
    if ((tid & 63) == 0) red[tid >> 6] = v;
    __syncthreads();
    if (tid == 0) {
        partials[(size_t)blockIdx.z * (GX * GY)
                 + (size_t)blockIdx.y * GX + blockIdx.x]
            = red[0] + red[1] + red[2] + red[3];
    }
}

__global__ __launch_bounds__(256) void reduce_final(
    const float* __restrict__ partials, int n, float* __restrict__ out)
{
    int tid = threadIdx.x;
    double s = 0.0;
    for (int i = tid; i < n; i += 256) s += (double)partials[i];
    #pragma unroll
    for (int o = 32; o > 0; o >>= 1) s += __shfl_down(s, o, 64);
    __shared__ double red[4];
    if ((tid & 63) == 0) red[tid >> 6] = s;
    __syncthreads();
    if (tid == 0) {
        double t = red[0] + red[1] + red[2] + red[3];
        const double ntot = (double)BATCH * (double)DEPTH * (double)H * (double)W;
        out[0] = (float)(t / ntot);
    }
}

extern "C" void kernel_launch(void* const* d_in, const int* in_sizes, int n_in,
                              void* d_out, int out_size, void* d_ws, size_t ws_size,
                              hipStream_t stream) {
    const float* pred = (const float*)d_in[0];
    const float* gt   = (const float*)d_in[1];
    const float* mask = (const float*)d_in[2];
    float* partials = (float*)d_ws;

    dim3 grid(GX, GY, BATCH);   // 36 x 16 x 2 = 1152
    sobel_loss_part<<<grid, 256, 0, stream>>>(pred, gt, mask, partials);

    reduce_final<<<1, 256, 0, stream>>>(partials, NBLK, (float*)d_out);
}